// Round 1
// baseline (423.316 us; speedup 1.0000x reference)
//
#include <hip/hip_runtime.h>
#include <cstdint>
#include <cstddef>

// ContrastiveLoss: B=8192, D=256 fp32 inputs.
// loss = mean_b [ log( exp(pos_b/T) + sum_c exp((z_i[b].z_k[c])/T) ) - pos_b/T ]
// pos_b = z_i[b].z_j[b],  T = 0.5  (so /T == *2)

constexpr int   D_DIM = 256;
constexpr float INV_T = 2.0f;   // 1/0.5

constexpr int BM = 128;
constexpr int BN = 128;
constexpr int BK = 32;

// ---------------------------------------------------------------------------
// Kernel 1: per-row inverse norms for emb_i / emb_k and pos_logit.
// One 64-lane wave per row; lane reads float4 (64*4 = 256 = D).
// ---------------------------------------------------------------------------
__global__ __launch_bounds__(256) void norm_pos_kernel(
    const float* __restrict__ ei, const float* __restrict__ ej,
    const float* __restrict__ ek,
    float* __restrict__ inv_i, float* __restrict__ inv_k,
    float* __restrict__ pos_logit, int B)
{
    const int w    = (int)((blockIdx.x * blockDim.x + threadIdx.x) >> 6);
    const int lane = (int)(threadIdx.x & 63);
    if (w >= B) return;

    const float4 vi = ((const float4*)(ei + (size_t)w * D_DIM))[lane];
    const float4 vj = ((const float4*)(ej + (size_t)w * D_DIM))[lane];
    const float4 vk = ((const float4*)(ek + (size_t)w * D_DIM))[lane];

    float ssi = vi.x*vi.x + vi.y*vi.y + vi.z*vi.z + vi.w*vi.w;
    float ssj = vj.x*vj.x + vj.y*vj.y + vj.z*vj.z + vj.w*vj.w;
    float ssk = vk.x*vk.x + vk.y*vk.y + vk.z*vk.z + vk.w*vk.w;
    float dij = vi.x*vj.x + vi.y*vj.y + vi.z*vj.z + vi.w*vj.w;

    #pragma unroll
    for (int off = 32; off; off >>= 1) {
        ssi += __shfl_xor(ssi, off);
        ssj += __shfl_xor(ssj, off);
        ssk += __shfl_xor(ssk, off);
        dij += __shfl_xor(dij, off);
    }

    if (lane == 0) {
        const float ni = fmaxf(sqrtf(ssi), 1e-12f);
        const float nj = fmaxf(sqrtf(ssj), 1e-12f);
        const float nk = fmaxf(sqrtf(ssk), 1e-12f);
        inv_i[w]      = 1.0f / ni;
        inv_k[w]      = 1.0f / nk;
        pos_logit[w]  = (dij / (ni * nj)) * INV_T;
    }
}

// ---------------------------------------------------------------------------
// Kernel 2: rowsum[b] += sum over a 128-column tile of exp(2 * z_i[b].z_k[c]).
// 128x128 block tile, 256 threads, 8x8 per-thread micro-tile (split 4+4).
// A/B tiles stored k-major in LDS ([BK][128]) so fragments are ds_read_b128.
// Normalization (inv_i/inv_k) folded into the LDS staging multiply.
// ---------------------------------------------------------------------------
__global__ __launch_bounds__(256) void sim_kernel(
    const float* __restrict__ ei, const float* __restrict__ ek,
    const float* __restrict__ inv_i, const float* __restrict__ inv_k,
    float* __restrict__ rowsum, int B)
{
    __shared__ float As[BK][BM];
    __shared__ float Bs[BK][BN];

    const int t  = (int)threadIdx.x;
    const int tx = t & 15;   // column group (0..15)
    const int ty = t >> 4;   // row group    (0..15)
    const int rowBase = (int)blockIdx.y * BM;
    const int colBase = (int)blockIdx.x * BN;

    // staging: one lane per tile row (sr 0..127); kg selects 16-wide k slice
    const int sr = t & 127;
    const int kg = t >> 7;          // 0 or 1 (wave-uniform)
    const float si = inv_i[rowBase + sr];
    const float sk = inv_k[colBase + sr];
    const float* gA = ei + (size_t)(rowBase + sr) * D_DIM + kg * 16;
    const float* gB = ek + (size_t)(colBase + sr) * D_DIM + kg * 16;

    float acc[8][8] = {};

    for (int k0 = 0; k0 < D_DIM; k0 += BK) {
        float4 a[4], b[4];
        #pragma unroll
        for (int q = 0; q < 4; ++q) {
            a[q] = *(const float4*)(gA + k0 + q * 4);
            b[q] = *(const float4*)(gB + k0 + q * 4);
        }
        __syncthreads();   // protect previous iteration's LDS reads
        #pragma unroll
        for (int q = 0; q < 4; ++q) {
            const int kq = kg * 16 + q * 4;
            As[kq + 0][sr] = a[q].x * si;
            As[kq + 1][sr] = a[q].y * si;
            As[kq + 2][sr] = a[q].z * si;
            As[kq + 3][sr] = a[q].w * si;
            Bs[kq + 0][sr] = b[q].x * sk;
            Bs[kq + 1][sr] = b[q].y * sk;
            Bs[kq + 2][sr] = b[q].z * sk;
            Bs[kq + 3][sr] = b[q].w * sk;
        }
        __syncthreads();

        #pragma unroll
        for (int kk = 0; kk < BK; ++kk) {
            const float4 a0 = *(const float4*)&As[kk][ty * 4];
            const float4 a1 = *(const float4*)&As[kk][64 + ty * 4];
            const float4 b0 = *(const float4*)&Bs[kk][tx * 4];
            const float4 b1 = *(const float4*)&Bs[kk][64 + tx * 4];
            const float av[8] = {a0.x, a0.y, a0.z, a0.w, a1.x, a1.y, a1.z, a1.w};
            const float bv[8] = {b0.x, b0.y, b0.z, b0.w, b1.x, b1.y, b1.z, b1.w};
            #pragma unroll
            for (int i2 = 0; i2 < 8; ++i2)
                #pragma unroll
                for (int j = 0; j < 8; ++j)
                    acc[i2][j] += av[i2] * bv[j];
        }
    }

    // epilogue: exp + per-row sum; reduce across the 16 column-threads (tx)
    #pragma unroll
    for (int i2 = 0; i2 < 8; ++i2) {
        float rs = 0.f;
        #pragma unroll
        for (int j = 0; j < 8; ++j)
            rs += expf(acc[i2][j] * INV_T);
        rs += __shfl_xor(rs, 1);
        rs += __shfl_xor(rs, 2);
        rs += __shfl_xor(rs, 4);
        rs += __shfl_xor(rs, 8);
        if (tx == 0) {
            const int r = rowBase + ((i2 < 4) ? (ty * 4 + i2)
                                              : (64 + ty * 4 + (i2 - 4)));
            atomicAdd(&rowsum[r], rs);
        }
    }
}

// ---------------------------------------------------------------------------
// Kernel 3: loss = mean_b [ log(exp(pos_b) + rowsum_b) - pos_b ]
// ---------------------------------------------------------------------------
__global__ __launch_bounds__(256) void finalize_kernel(
    const float* __restrict__ pos_logit, const float* __restrict__ rowsum,
    float* __restrict__ out, int B)
{
    __shared__ float red[256];
    float acc = 0.f;
    for (int b = (int)threadIdx.x; b < B; b += 256) {
        const float pl = pos_logit[b];
        acc += logf(expf(pl) + rowsum[b]) - pl;
    }
    red[threadIdx.x] = acc;
    __syncthreads();
    #pragma unroll
    for (int s = 128; s; s >>= 1) {
        if ((int)threadIdx.x < s) red[threadIdx.x] += red[threadIdx.x + s];
        __syncthreads();
    }
    if (threadIdx.x == 0) out[0] = red[0] / (float)B;
}

// ---------------------------------------------------------------------------
extern "C" void kernel_launch(void* const* d_in, const int* in_sizes, int n_in,
                              void* d_out, int out_size, void* d_ws, size_t ws_size,
                              hipStream_t stream)
{
    const float* ei = (const float*)d_in[0];
    const float* ej = (const float*)d_in[1];
    const float* ek = (const float*)d_in[2];
    const int B = in_sizes[0] / D_DIM;   // 8192

    float* ws        = (float*)d_ws;
    float* inv_i     = ws;
    float* inv_k     = ws + B;
    float* pos_logit = ws + 2 * B;
    float* rowsum    = ws + 3 * B;

    hipMemsetAsync(rowsum, 0, (size_t)B * sizeof(float), stream);

    norm_pos_kernel<<<dim3((B + 3) / 4), dim3(256), 0, stream>>>(
        ei, ej, ek, inv_i, inv_k, pos_logit, B);

    dim3 grid(B / BN, B / BM);
    sim_kernel<<<grid, dim3(256), 0, stream>>>(ei, ek, inv_i, inv_k, rowsum, B);

    finalize_kernel<<<dim3(1), dim3(256), 0, stream>>>(
        pos_logit, rowsum, (float*)d_out, B);
}

// Round 2
// 138.424 us; speedup vs baseline: 3.0581x; 3.0581x over previous
//
#include <hip/hip_runtime.h>
#include <cstdint>
#include <cstddef>

// ContrastiveLoss: B=8192, D=256 fp32 inputs.
// loss = mean_b [ log( exp(pos_b*2) + sum_c exp(2*z_i[b].z_k[c]) ) - pos_b*2 ]
// Strategy: prep -> bf16 normalized Z_i/Z_k; MFMA GEMM (m97 structure) with
// fused exp+rowsum epilogue; scalar finalize.

constexpr int   D_DIM = 256;
constexpr float INV_T = 2.0f;   // 1/T, T=0.5

constexpr int BM = 128;
constexpr int BN = 128;
constexpr int BK = 32;

typedef __attribute__((ext_vector_type(8))) short  bf16x8;
typedef __attribute__((ext_vector_type(4))) float  f32x4;

__device__ __forceinline__ unsigned short f32_to_bf16(float f) {
    unsigned int u = __float_as_uint(f);
    u += 0x7FFFu + ((u >> 16) & 1u);          // RNE
    return (unsigned short)(u >> 16);
}

// CK-proven pattern: generic->AS1/AS3 via uintptr_t round-trip.
__device__ __forceinline__ void gload_lds16(const void* g, void* l) {
    auto gp = reinterpret_cast<const __attribute__((address_space(1))) unsigned int*>(
        reinterpret_cast<uintptr_t>(g));
    auto lp = reinterpret_cast<__attribute__((address_space(3))) unsigned int*>(
        reinterpret_cast<uintptr_t>(l));
    __builtin_amdgcn_global_load_lds(gp, lp, 16 /*bytes: dwordx4*/, 0, 0);
}

// ---------------------------------------------------------------------------
// Kernel 1: per-row norms; write normalized bf16 z_i, z_k; fp32 pos_logit.
// One 64-lane wave per row; lane handles 4 elements (float4).
// ---------------------------------------------------------------------------
__global__ __launch_bounds__(256) void prep_kernel(
    const float* __restrict__ ei, const float* __restrict__ ej,
    const float* __restrict__ ek,
    unsigned short* __restrict__ zi, unsigned short* __restrict__ zk,
    float* __restrict__ pos_logit, int B)
{
    const int w    = (int)((blockIdx.x * blockDim.x + threadIdx.x) >> 6);
    const int lane = (int)(threadIdx.x & 63);
    if (w >= B) return;

    const float4 vi = ((const float4*)(ei + (size_t)w * D_DIM))[lane];
    const float4 vj = ((const float4*)(ej + (size_t)w * D_DIM))[lane];
    const float4 vk = ((const float4*)(ek + (size_t)w * D_DIM))[lane];

    float ssi = vi.x*vi.x + vi.y*vi.y + vi.z*vi.z + vi.w*vi.w;
    float ssj = vj.x*vj.x + vj.y*vj.y + vj.z*vj.z + vj.w*vj.w;
    float ssk = vk.x*vk.x + vk.y*vk.y + vk.z*vk.z + vk.w*vk.w;
    float dij = vi.x*vj.x + vi.y*vj.y + vi.z*vj.z + vi.w*vj.w;

    #pragma unroll
    for (int off = 32; off; off >>= 1) {
        ssi += __shfl_xor(ssi, off);
        ssj += __shfl_xor(ssj, off);
        ssk += __shfl_xor(ssk, off);
        dij += __shfl_xor(dij, off);
    }
    // butterfly leaves full sums in every lane — no broadcast needed
    const float ri = 1.0f / fmaxf(sqrtf(ssi), 1e-12f);
    const float rj = 1.0f / fmaxf(sqrtf(ssj), 1e-12f);
    const float rk = 1.0f / fmaxf(sqrtf(ssk), 1e-12f);

    ushort4 oi, ok;
    oi.x = f32_to_bf16(vi.x * ri); oi.y = f32_to_bf16(vi.y * ri);
    oi.z = f32_to_bf16(vi.z * ri); oi.w = f32_to_bf16(vi.w * ri);
    ok.x = f32_to_bf16(vk.x * rk); ok.y = f32_to_bf16(vk.y * rk);
    ok.z = f32_to_bf16(vk.z * rk); ok.w = f32_to_bf16(vk.w * rk);
    ((ushort4*)(zi + (size_t)w * D_DIM))[lane] = oi;
    ((ushort4*)(zk + (size_t)w * D_DIM))[lane] = ok;

    if (lane == 0) pos_logit[w] = dij * ri * rj * INV_T;
}

// ---------------------------------------------------------------------------
// Kernel 2: m97-structure bf16 MFMA GEMM over C = Z_i . Z_k^T (both row-major,
// K contiguous) + fused exp/rowsum epilogue.
// 128x128 block tile, 4 waves (2x2), each wave 64x64 = 4x4 fragments of
// 16x16x32. Staging via global_load_lds width 16 into linear LDS [row][k].
// ---------------------------------------------------------------------------
__global__ __launch_bounds__(256) void sim_mfma_kernel(
    const unsigned short* __restrict__ zi, const unsigned short* __restrict__ zk,
    float* __restrict__ rowsum)
{
    __shared__ unsigned short As[BM * BK];   // [row][k], 64 B/row
    __shared__ unsigned short Bs[BN * BK];

    const int t  = (int)threadIdx.x;
    const int w  = t >> 6;        // wave 0..3
    const int l  = t & 63;
    const int wr = w >> 1;        // wave row   (0..1)
    const int wc = w & 1;         // wave col   (0..1)
    const int rowBase = (int)blockIdx.y * BM;
    const int colBase = (int)blockIdx.x * BN;

    // staging: wave w, instr q in {0,1}: lds bytes [(w*2+q)*1024, +1024)
    // lane l writes 16 B at +l*16  ->  row (w*2+q)*16 + (l>>2), k elem (l&3)*8
    const unsigned short* gA =
        zi + (size_t)(rowBase + w * 32 + (l >> 2)) * D_DIM + (l & 3) * 8;
    const unsigned short* gB =
        zk + (size_t)(colBase + w * 32 + (l >> 2)) * D_DIM + (l & 3) * 8;
    unsigned short* lA = &As[w * 1024];      // elements (2 B each)
    unsigned short* lB = &Bs[w * 1024];

    f32x4 acc[4][4] = {};

    const int rA = l & 15;          // fragment row/col within 16
    const int ks = (l >> 4) * 8;    // k slice

    for (int k0 = 0; k0 < D_DIM; k0 += BK) {
        gload_lds16(gA + k0,              lA);
        gload_lds16(gA + k0 + 16 * D_DIM, lA + 512);
        gload_lds16(gB + k0,              lB);
        gload_lds16(gB + k0 + 16 * D_DIM, lB + 512);
        __syncthreads();   // drain vmcnt + barrier: tiles ready

        bf16x8 af[4], bfr[4];
        #pragma unroll
        for (int mi = 0; mi < 4; ++mi)
            af[mi] = *(const bf16x8*)&As[(wr * 64 + mi * 16 + rA) * BK + ks];
        #pragma unroll
        for (int ni = 0; ni < 4; ++ni)
            bfr[ni] = *(const bf16x8*)&Bs[(wc * 64 + ni * 16 + rA) * BK + ks];

        #pragma unroll
        for (int mi = 0; mi < 4; ++mi)
            #pragma unroll
            for (int ni = 0; ni < 4; ++ni)
                acc[mi][ni] = __builtin_amdgcn_mfma_f32_16x16x32_bf16(
                    af[mi], bfr[ni], acc[mi][ni], 0, 0, 0);

        __syncthreads();   // compute done: safe to overwrite tiles
    }

    // Epilogue: C/D layout col = l&15, row = (l>>4)*4 + reg.
    // part[mi][r] = sum over this lane's 4 columns of exp(2*s).
    float part[4][4];
    #pragma unroll
    for (int mi = 0; mi < 4; ++mi)
        #pragma unroll
        for (int r = 0; r < 4; ++r) {
            float s = 0.f;
            #pragma unroll
            for (int ni = 0; ni < 4; ++ni)
                s += __expf(INV_T * acc[mi][ni][r]);
            part[mi][r] = s;
        }
    // reduce across the 16 column-lanes (l&15)
    #pragma unroll
    for (int off = 1; off <= 8; off <<= 1)
        #pragma unroll
        for (int mi = 0; mi < 4; ++mi)
            #pragma unroll
            for (int r = 0; r < 4; ++r)
                part[mi][r] += __shfl_xor(part[mi][r], off);

    if ((l & 15) == 0) {
        const int rg = (l >> 4) * 4;
        #pragma unroll
        for (int mi = 0; mi < 4; ++mi)
            #pragma unroll
            for (int r = 0; r < 4; ++r)
                atomicAdd(&rowsum[rowBase + wr * 64 + mi * 16 + rg + r],
                          part[mi][r]);
    }
}

// ---------------------------------------------------------------------------
// Kernel 3: loss = mean_b [ log(exp(pos_b) + rowsum_b) - pos_b ]
// ---------------------------------------------------------------------------
__global__ __launch_bounds__(256) void finalize_kernel(
    const float* __restrict__ pos_logit, const float* __restrict__ rowsum,
    float* __restrict__ out, int B)
{
    __shared__ float red[256];
    float acc = 0.f;
    for (int b = (int)threadIdx.x; b < B; b += 256) {
        const float pl = pos_logit[b];
        acc += logf(expf(pl) + rowsum[b]) - pl;
    }
    red[threadIdx.x] = acc;
    __syncthreads();
    #pragma unroll
    for (int s = 128; s; s >>= 1) {
        if ((int)threadIdx.x < s) red[threadIdx.x] += red[threadIdx.x + s];
        __syncthreads();
    }
    if (threadIdx.x == 0) out[0] = red[0] / (float)B;
}

// ---------------------------------------------------------------------------
extern "C" void kernel_launch(void* const* d_in, const int* in_sizes, int n_in,
                              void* d_out, int out_size, void* d_ws, size_t ws_size,
                              hipStream_t stream)
{
    const float* ei = (const float*)d_in[0];
    const float* ej = (const float*)d_in[1];
    const float* ek = (const float*)d_in[2];
    const int B = in_sizes[0] / D_DIM;   // 8192

    unsigned short* zi = (unsigned short*)d_ws;
    unsigned short* zk = zi + (size_t)B * D_DIM;
    float* rowsum      = (float*)(zk + (size_t)B * D_DIM);
    float* pos_logit   = rowsum + B;

    hipMemsetAsync(rowsum, 0, (size_t)B * sizeof(float), stream);

    prep_kernel<<<dim3((B + 3) / 4), dim3(256), 0, stream>>>(
        ei, ej, ek, zi, zk, pos_logit, B);

    dim3 grid(B / BN, B / BM);
    sim_mfma_kernel<<<grid, dim3(256), 0, stream>>>(zi, zk, rowsum);

    finalize_kernel<<<dim3(1), dim3(256), 0, stream>>>(
        pos_logit, rowsum, (float*)d_out, B);
}

// Round 3
// 125.678 us; speedup vs baseline: 3.3683x; 1.1014x over previous
//
#include <hip/hip_runtime.h>
#include <cstdint>
#include <cstddef>

// ContrastiveLoss: B=8192, D=256 fp32 inputs.
// loss = mean_b [ log( exp(pos_b*2) + sum_c exp(2*z_i[b].z_k[c]) ) - pos_b*2 ]
// R2: bf16 MFMA GEMM, 128x128 tile, BK=32, double-buffered LDS with
// counted-vmcnt prefetch (T3/T4 minimum 2-phase) + uniform XOR swizzle (T2,
// both-sides via pre-swizzled global source per rule 21).

constexpr int   D_DIM = 256;
constexpr float INV_T = 2.0f;   // 1/T, T=0.5

constexpr int BM = 128;
constexpr int BN = 128;
constexpr int BK = 32;

typedef __attribute__((ext_vector_type(8))) short  bf16x8;
typedef __attribute__((ext_vector_type(4))) float  f32x4;

__device__ __forceinline__ unsigned short f32_to_bf16(float f) {
    unsigned int u = __float_as_uint(f);
    u += 0x7FFFu + ((u >> 16) & 1u);          // RNE
    return (unsigned short)(u >> 16);
}

__device__ __forceinline__ void gload_lds16(const void* g, void* l) {
    auto gp = reinterpret_cast<const __attribute__((address_space(1))) unsigned int*>(
        reinterpret_cast<uintptr_t>(g));
    auto lp = reinterpret_cast<__attribute__((address_space(3))) unsigned int*>(
        reinterpret_cast<uintptr_t>(l));
    __builtin_amdgcn_global_load_lds(gp, lp, 16, 0, 0);
}

// ---------------------------------------------------------------------------
// Kernel 1: per-row norms; write normalized bf16 z_i, z_k; fp32 pos_logit.
// ---------------------------------------------------------------------------
__global__ __launch_bounds__(256) void prep_kernel(
    const float* __restrict__ ei, const float* __restrict__ ej,
    const float* __restrict__ ek,
    unsigned short* __restrict__ zi, unsigned short* __restrict__ zk,
    float* __restrict__ pos_logit, int B)
{
    const int w    = (int)((blockIdx.x * blockDim.x + threadIdx.x) >> 6);
    const int lane = (int)(threadIdx.x & 63);
    if (w >= B) return;

    const float4 vi = ((const float4*)(ei + (size_t)w * D_DIM))[lane];
    const float4 vj = ((const float4*)(ej + (size_t)w * D_DIM))[lane];
    const float4 vk = ((const float4*)(ek + (size_t)w * D_DIM))[lane];

    float ssi = vi.x*vi.x + vi.y*vi.y + vi.z*vi.z + vi.w*vi.w;
    float ssj = vj.x*vj.x + vj.y*vj.y + vj.z*vj.z + vj.w*vj.w;
    float ssk = vk.x*vk.x + vk.y*vk.y + vk.z*vk.z + vk.w*vk.w;
    float dij = vi.x*vj.x + vi.y*vj.y + vi.z*vj.z + vi.w*vj.w;

    #pragma unroll
    for (int off = 32; off; off >>= 1) {
        ssi += __shfl_xor(ssi, off);
        ssj += __shfl_xor(ssj, off);
        ssk += __shfl_xor(ssk, off);
        dij += __shfl_xor(dij, off);
    }
    const float ri = 1.0f / fmaxf(sqrtf(ssi), 1e-12f);
    const float rj = 1.0f / fmaxf(sqrtf(ssj), 1e-12f);
    const float rk = 1.0f / fmaxf(sqrtf(ssk), 1e-12f);

    ushort4 oi, ok;
    oi.x = f32_to_bf16(vi.x * ri); oi.y = f32_to_bf16(vi.y * ri);
    oi.z = f32_to_bf16(vi.z * ri); oi.w = f32_to_bf16(vi.w * ri);
    ok.x = f32_to_bf16(vk.x * rk); ok.y = f32_to_bf16(vk.y * rk);
    ok.z = f32_to_bf16(vk.z * rk); ok.w = f32_to_bf16(vk.w * rk);
    ((ushort4*)(zi + (size_t)w * D_DIM))[lane] = oi;
    ((ushort4*)(zk + (size_t)w * D_DIM))[lane] = ok;

    if (lane == 0) pos_logit[w] = dij * ri * rj * INV_T;
}

// ---------------------------------------------------------------------------
// Kernel 2: C = Z_i . Z_k^T via bf16 MFMA + fused exp/rowsum epilogue.
// 128x128 tile, 4 waves (2x2, each 64x64 = 4x4 frags of 16x16x32), BK=32,
// double-buffered LDS, counted vmcnt(4), raw s_barrier.
// Swizzle: LDS[row][c] holds global[row][c ^ 8*((row>>1)&3)] (elems);
// achieved by pre-swizzling the per-lane GLOBAL source of global_load_lds
// (LDS dest stays linear). Reads apply the same XOR -> uniform bank use.
// ---------------------------------------------------------------------------
__global__ __launch_bounds__(256) void sim_mfma_kernel(
    const unsigned short* __restrict__ zi, const unsigned short* __restrict__ zk,
    float* __restrict__ rowsum)
{
    __shared__ unsigned short As[2][BM * BK];   // 8 KB each
    __shared__ unsigned short Bs[2][BN * BK];

    const int t  = (int)threadIdx.x;
    const int w  = t >> 6;        // wave 0..3
    const int l  = t & 63;
    const int wr = w >> 1;        // wave row (0..1)
    const int wc = w & 1;         // wave col (0..1)
    const int rowBase = (int)blockIdx.y * BM;
    const int colBase = (int)blockIdx.x * BN;

    // ---- staging addresses (per-lane constants) ----
    // wave w, instr q in {0,1}: rows [w*32+q*16, +16); lane l -> row +(l>>2),
    // 16B at col (l&3)*16. Source col pre-swizzled: elems 8*((l&3)^((l>>3)&3)).
    const int csrc = 8 * ((l & 3) ^ ((l >> 3) & 3));
    const unsigned short* gA0 =
        zi + (size_t)(rowBase + w * 32 + (l >> 2)) * D_DIM + csrc;
    const unsigned short* gA1 = gA0 + 16 * D_DIM;
    const unsigned short* gB0 =
        zk + (size_t)(colBase + w * 32 + (l >> 2)) * D_DIM + csrc;
    const unsigned short* gB1 = gB0 + 16 * D_DIM;
    const int bQ0 = w * 1024;          // LDS element base, q=0 (wave-uniform)
    const int bQ1 = w * 1024 + 512;    // q=1

    // ---- fragment read offsets (per-lane constants) ----
    const int rA = l & 15;                          // row/col within fragment
    const int ce = 8 * ((l >> 4) ^ ((rA >> 1) & 3)); // swizzled k-col (elems)

    f32x4 acc[4][4] = {};

    #define STAGE(b, k0)                               \
        gload_lds16(gA0 + (k0), &As[b][bQ0]);          \
        gload_lds16(gA1 + (k0), &As[b][bQ1]);          \
        gload_lds16(gB0 + (k0), &Bs[b][bQ0]);          \
        gload_lds16(gB1 + (k0), &Bs[b][bQ1]);

    STAGE(0, 0);                       // prologue: tile 0 -> buf 0
    int cur = 0;

    #pragma unroll
    for (int kt = 0; kt < 8; ++kt) {
        const int kn = ((kt + 1) & 7) * BK;   // wrap: kt=7 restages tile 0
        STAGE(cur ^ 1, kn);
        asm volatile("s_waitcnt vmcnt(4)" ::: "memory");  // cur tile landed
        __builtin_amdgcn_s_barrier();

        bf16x8 af[4], bfr[4];
        #pragma unroll
        for (int mi = 0; mi < 4; ++mi)
            af[mi] = *(const bf16x8*)&As[cur][(wr * 64 + mi * 16 + rA) * BK + ce];
        #pragma unroll
        for (int ni = 0; ni < 4; ++ni)
            bfr[ni] = *(const bf16x8*)&Bs[cur][(wc * 64 + ni * 16 + rA) * BK + ce];

        #pragma unroll
        for (int mi = 0; mi < 4; ++mi)
            #pragma unroll
            for (int ni = 0; ni < 4; ++ni)
                acc[mi][ni] = __builtin_amdgcn_mfma_f32_16x16x32_bf16(
                    af[mi], bfr[ni], acc[mi][ni], 0, 0, 0);

        __builtin_amdgcn_sched_barrier(0);   // pin reads+MFMAs above barrier
        asm volatile("" ::: "memory");
        __builtin_amdgcn_s_barrier();        // cur buffer free for restage
        cur ^= 1;
    }
    #undef STAGE

    // Epilogue: C/D layout col = l&15, row = (l>>4)*4 + reg.
    float part[4][4];
    #pragma unroll
    for (int mi = 0; mi < 4; ++mi)
        #pragma unroll
        for (int r = 0; r < 4; ++r) {
            float s = 0.f;
            #pragma unroll
            for (int ni = 0; ni < 4; ++ni)
                s += __expf(INV_T * acc[mi][ni][r]);
            part[mi][r] = s;
        }
    #pragma unroll
    for (int off = 1; off <= 8; off <<= 1)
        #pragma unroll
        for (int mi = 0; mi < 4; ++mi)
            #pragma unroll
            for (int r = 0; r < 4; ++r)
                part[mi][r] += __shfl_xor(part[mi][r], off);

    if ((l & 15) == 0) {
        const int rg = (l >> 4) * 4;
        #pragma unroll
        for (int mi = 0; mi < 4; ++mi)
            #pragma unroll
            for (int r = 0; r < 4; ++r)
                atomicAdd(&rowsum[rowBase + wr * 64 + mi * 16 + rg + r],
                          part[mi][r]);
    }
}

// ---------------------------------------------------------------------------
// Kernel 3: loss = mean_b [ log(exp(pos_b) + rowsum_b) - pos_b ]
// ---------------------------------------------------------------------------
__global__ __launch_bounds__(256) void finalize_kernel(
    const float* __restrict__ pos_logit, const float* __restrict__ rowsum,
    float* __restrict__ out, int B)
{
    __shared__ float red[256];
    float acc = 0.f;
    for (int b = (int)threadIdx.x; b < B; b += 256) {
        const float pl = pos_logit[b];
        acc += logf(expf(pl) + rowsum[b]) - pl;
    }
    red[threadIdx.x] = acc;
    __syncthreads();
    #pragma unroll
    for (int s = 128; s; s >>= 1) {
        if ((int)threadIdx.x < s) red[threadIdx.x] += red[threadIdx.x + s];
        __syncthreads();
    }
    if (threadIdx.x == 0) out[0] = red[0] / (float)B;
}

// ---------------------------------------------------------------------------
extern "C" void kernel_launch(void* const* d_in, const int* in_sizes, int n_in,
                              void* d_out, int out_size, void* d_ws, size_t ws_size,
                              hipStream_t stream)
{
    const float* ei = (const float*)d_in[0];
    const float* ej = (const float*)d_in[1];
    const float* ek = (const float*)d_in[2];
    const int B = in_sizes[0] / D_DIM;   // 8192

    unsigned short* zi = (unsigned short*)d_ws;
    unsigned short* zk = zi + (size_t)B * D_DIM;
    float* rowsum      = (float*)(zk + (size_t)B * D_DIM);
    float* pos_logit   = rowsum + B;

    hipMemsetAsync(rowsum, 0, (size_t)B * sizeof(float), stream);

    prep_kernel<<<dim3((B + 3) / 4), dim3(256), 0, stream>>>(
        ei, ej, ek, zi, zk, pos_logit, B);

    dim3 grid(B / BN, B / BM);
    sim_mfma_kernel<<<grid, dim3(256), 0, stream>>>(zi, zk, rowsum);

    finalize_kernel<<<dim3(1), dim3(256), 0, stream>>>(
        pos_logit, rowsum, (float*)d_out, B);
}

// Round 4
// 55.465 us; speedup vs baseline: 7.6322x; 2.2659x over previous
//
#include <hip/hip_runtime.h>
#include <cstdint>
#include <cstddef>

// ContrastiveLoss: B=8192, D=256 fp32 inputs.
// loss = mean_b [ log( exp(pos_b*2) + sum_c exp(2*z_i[b].z_k[c]) ) - pos_b*2 ]
// R3: persistent-A flash-style MFMA GEMM. Each block: 128-row panel, A panel
// (128x256) resident in LDS (8 swizzled sub-tiles, 64 KB), streams 8 column
// tiles (128 cols each) through a 2-phase B double-buffer with counted vmcnt.
// exp fused per tile; shuffle-reduce + atomics once per block.

constexpr int   D_DIM = 256;
constexpr float INV_T = 2.0f;   // 1/T, T=0.5

constexpr int BM = 128;
constexpr int BN = 128;
constexpr int BK = 32;
constexpr int NT = 8;           // column tiles per block

typedef __attribute__((ext_vector_type(8))) short  bf16x8;
typedef __attribute__((ext_vector_type(4))) float  f32x4;

__device__ __forceinline__ unsigned short f32_to_bf16(float f) {
    unsigned int u = __float_as_uint(f);
    u += 0x7FFFu + ((u >> 16) & 1u);          // RNE
    return (unsigned short)(u >> 16);
}

__device__ __forceinline__ void gload_lds16(const void* g, void* l) {
    auto gp = reinterpret_cast<const __attribute__((address_space(1))) unsigned int*>(
        reinterpret_cast<uintptr_t>(g));
    auto lp = reinterpret_cast<__attribute__((address_space(3))) unsigned int*>(
        reinterpret_cast<uintptr_t>(l));
    __builtin_amdgcn_global_load_lds(gp, lp, 16, 0, 0);
}

// ---------------------------------------------------------------------------
// Kernel 1: per-row norms; write normalized bf16 z_i, z_k; fp32 pos_logit.
// Also zero-initializes rowsum (replaces hipMemsetAsync dispatch).
// ---------------------------------------------------------------------------
__global__ __launch_bounds__(256) void prep_kernel(
    const float* __restrict__ ei, const float* __restrict__ ej,
    const float* __restrict__ ek,
    unsigned short* __restrict__ zi, unsigned short* __restrict__ zk,
    float* __restrict__ pos_logit, float* __restrict__ rowsum, int B)
{
    const int w    = (int)((blockIdx.x * blockDim.x + threadIdx.x) >> 6);
    const int lane = (int)(threadIdx.x & 63);
    if (w >= B) return;

    const float4 vi = ((const float4*)(ei + (size_t)w * D_DIM))[lane];
    const float4 vj = ((const float4*)(ej + (size_t)w * D_DIM))[lane];
    const float4 vk = ((const float4*)(ek + (size_t)w * D_DIM))[lane];

    float ssi = vi.x*vi.x + vi.y*vi.y + vi.z*vi.z + vi.w*vi.w;
    float ssj = vj.x*vj.x + vj.y*vj.y + vj.z*vj.z + vj.w*vj.w;
    float ssk = vk.x*vk.x + vk.y*vk.y + vk.z*vk.z + vk.w*vk.w;
    float dij = vi.x*vj.x + vi.y*vj.y + vi.z*vj.z + vi.w*vj.w;

    #pragma unroll
    for (int off = 32; off; off >>= 1) {
        ssi += __shfl_xor(ssi, off);
        ssj += __shfl_xor(ssj, off);
        ssk += __shfl_xor(ssk, off);
        dij += __shfl_xor(dij, off);
    }
    const float ri = 1.0f / fmaxf(sqrtf(ssi), 1e-12f);
    const float rj = 1.0f / fmaxf(sqrtf(ssj), 1e-12f);
    const float rk = 1.0f / fmaxf(sqrtf(ssk), 1e-12f);

    ushort4 oi, ok;
    oi.x = f32_to_bf16(vi.x * ri); oi.y = f32_to_bf16(vi.y * ri);
    oi.z = f32_to_bf16(vi.z * ri); oi.w = f32_to_bf16(vi.w * ri);
    ok.x = f32_to_bf16(vk.x * rk); ok.y = f32_to_bf16(vk.y * rk);
    ok.z = f32_to_bf16(vk.z * rk); ok.w = f32_to_bf16(vk.w * rk);
    ((ushort4*)(zi + (size_t)w * D_DIM))[lane] = oi;
    ((ushort4*)(zk + (size_t)w * D_DIM))[lane] = ok;

    if (lane == 0) {
        pos_logit[w] = dij * ri * rj * INV_T;
        rowsum[w]    = 0.0f;
    }
}

// ---------------------------------------------------------------------------
// Kernel 2: rows [by*128,+128) x cols [bx*1024,+1024) of C = Z_i . Z_k^T.
// A panel resident (Afull, 8 sub-tiles of the verified swizzled [128][32]
// layout); B streamed over 64 steps (8 tiles x 8 K-steps), dbuf + vmcnt(2).
// 4 waves (2x2), each 64x64 = 4x4 frags of 16x16x32 bf16 MFMA.
// Swizzle (verified R2, conflicts=0): LDS[row][c] = global[row][c ^ swz(row)],
// via pre-swizzled global source (linear LDS dest, rule 21).
// ---------------------------------------------------------------------------
__global__ __launch_bounds__(256) void sim_mfma_kernel(
    const unsigned short* __restrict__ zi, const unsigned short* __restrict__ zk,
    float* __restrict__ rowsum)
{
    __shared__ unsigned short Afull[8][BM * BK];   // 64 KB
    __shared__ unsigned short Bs[2][BN * BK];      // 16 KB

    const int t  = (int)threadIdx.x;
    const int w  = t >> 6;        // wave 0..3
    const int l  = t & 63;
    const int wr = w >> 1;        // wave row (0..1)
    const int wc = w & 1;         // wave col (0..1)
    const int rowBase = (int)blockIdx.y * BM;
    const int colBase = (int)blockIdx.x * (NT * BN);

    // staging: wave w, instr q in {0,1}: rows [w*32+q*16,+16); lane l -> row
    // +(l>>2), 16B unit (l&3); source col pre-swizzled.
    const int csrc = 8 * ((l & 3) ^ ((l >> 3) & 3));
    const unsigned short* gA0 =
        zi + (size_t)(rowBase + w * 32 + (l >> 2)) * D_DIM + csrc;
    const unsigned short* gA1 = gA0 + 16 * D_DIM;
    const unsigned short* gB0 =
        zk + (size_t)(colBase + w * 32 + (l >> 2)) * D_DIM + csrc;
    const unsigned short* gB1 = gB0 + 16 * D_DIM;
    const int bQ0 = w * 1024;          // LDS element base (wave-uniform)
    const int bQ1 = bQ0 + 512;

    // prologue: stage full A panel (16 loads/wave) + B step 0 (2 loads/wave)
    #pragma unroll
    for (int kt = 0; kt < 8; ++kt) {
        gload_lds16(gA0 + kt * BK, &Afull[kt][bQ0]);
        gload_lds16(gA1 + kt * BK, &Afull[kt][bQ1]);
    }
    gload_lds16(gB0, &Bs[0][bQ0]);
    gload_lds16(gB1, &Bs[0][bQ1]);

    // fragment read offsets
    const int rA = l & 15;                           // row/col within fragment
    const int ce = 8 * ((l >> 4) ^ ((rA >> 1) & 3)); // swizzled k-col (elems)

    float partAcc[4][4] = {};    // per-(mi,reg) running exp-sums across tiles

    for (int nt = 0; nt < NT; ++nt) {
        f32x4 acc[4][4] = {};
        int cur = 0;             // starts 0 every tile (8 flips/tile)

        #pragma unroll
        for (int kt = 0; kt < 8; ++kt) {
            // prefetch next step (clamped restage at the very end: harmless)
            int s1 = nt * 8 + kt + 1;
            if (s1 > 63) s1 = 63;
            const size_t off =
                (size_t)(s1 >> 3) * (BN * D_DIM) + (size_t)(s1 & 7) * BK;
            gload_lds16(gB0 + off, &Bs[cur ^ 1][bQ0]);
            gload_lds16(gB1 + off, &Bs[cur ^ 1][bQ1]);
            asm volatile("s_waitcnt vmcnt(2)" ::: "memory");
            __builtin_amdgcn_s_barrier();

            bf16x8 af[4], bfr[4];
            #pragma unroll
            for (int mi = 0; mi < 4; ++mi)
                af[mi] = *(const bf16x8*)
                    &Afull[kt][(wr * 64 + mi * 16 + rA) * BK + ce];
            #pragma unroll
            for (int ni = 0; ni < 4; ++ni)
                bfr[ni] = *(const bf16x8*)
                    &Bs[cur][(wc * 64 + ni * 16 + rA) * BK + ce];

            #pragma unroll
            for (int mi = 0; mi < 4; ++mi)
                #pragma unroll
                for (int ni = 0; ni < 4; ++ni)
                    acc[mi][ni] = __builtin_amdgcn_mfma_f32_16x16x32_bf16(
                        af[mi], bfr[ni], acc[mi][ni], 0, 0, 0);

            __builtin_amdgcn_sched_barrier(0);   // keep reads+MFMAs here
            asm volatile("" ::: "memory");
            __builtin_amdgcn_s_barrier();        // cur buffer free to restage
            cur ^= 1;
        }

        // per-tile epilogue: exp + in-lane partial sums (no shuffles here)
        #pragma unroll
        for (int mi = 0; mi < 4; ++mi)
            #pragma unroll
            for (int r = 0; r < 4; ++r) {
                float s = 0.f;
                #pragma unroll
                for (int ni = 0; ni < 4; ++ni)
                    s += __expf(INV_T * acc[mi][ni][r]);
                partAcc[mi][r] += s;
            }
    }

    // block epilogue: reduce across the 16 column-lanes, one atomic set
    #pragma unroll
    for (int off = 1; off <= 8; off <<= 1)
        #pragma unroll
        for (int mi = 0; mi < 4; ++mi)
            #pragma unroll
            for (int r = 0; r < 4; ++r)
                partAcc[mi][r] += __shfl_xor(partAcc[mi][r], off);

    if ((l & 15) == 0) {
        const int rg = (l >> 4) * 4;     // C/D layout: row = (l>>4)*4 + reg
        #pragma unroll
        for (int mi = 0; mi < 4; ++mi)
            #pragma unroll
            for (int r = 0; r < 4; ++r)
                atomicAdd(&rowsum[rowBase + wr * 64 + mi * 16 + rg + r],
                          partAcc[mi][r]);
    }
}

// ---------------------------------------------------------------------------
// Kernel 3: loss = mean_b [ log(exp(pos_b) + rowsum_b) - pos_b ]
// ---------------------------------------------------------------------------
__global__ __launch_bounds__(1024) void finalize_kernel(
    const float* __restrict__ pos_logit, const float* __restrict__ rowsum,
    float* __restrict__ out, int B)
{
    __shared__ float red[1024];
    float acc = 0.f;
    for (int b = (int)threadIdx.x; b < B; b += 1024) {
        const float pl = pos_logit[b];
        acc += logf(expf(pl) + rowsum[b]) - pl;
    }
    red[threadIdx.x] = acc;
    __syncthreads();
    #pragma unroll
    for (int s = 512; s; s >>= 1) {
        if ((int)threadIdx.x < s) red[threadIdx.x] += red[threadIdx.x + s];
        __syncthreads();
    }
    if (threadIdx.x == 0) out[0] = red[0] / (float)B;
}

// ---------------------------------------------------------------------------
extern "C" void kernel_launch(void* const* d_in, const int* in_sizes, int n_in,
                              void* d_out, int out_size, void* d_ws, size_t ws_size,
                              hipStream_t stream)
{
    const float* ei = (const float*)d_in[0];
    const float* ej = (const float*)d_in[1];
    const float* ek = (const float*)d_in[2];
    const int B = in_sizes[0] / D_DIM;   // 8192

    unsigned short* zi = (unsigned short*)d_ws;
    unsigned short* zk = zi + (size_t)B * D_DIM;
    float* rowsum      = (float*)(zk + (size_t)B * D_DIM);
    float* pos_logit   = rowsum + B;

    prep_kernel<<<dim3((B + 3) / 4), dim3(256), 0, stream>>>(
        ei, ej, ek, zi, zk, pos_logit, rowsum, B);

    dim3 grid(B / (NT * BN), B / BM);    // (8, 64) = 512 blocks = 2/CU
    sim_mfma_kernel<<<grid, dim3(256), 0, stream>>>(zi, zk, rowsum);

    finalize_kernel<<<dim3(1), dim3(1024), 0, stream>>>(
        pos_logit, rowsum, (float*)d_out, B);
}

// Round 5
// 54.736 us; speedup vs baseline: 7.7337x; 1.0133x over previous
//
#include <hip/hip_runtime.h>
#include <cstdint>
#include <cstddef>

// ContrastiveLoss: B=8192, D=256 fp32 inputs.
// loss = mean_b [ log( exp(pos_b*2) + sum_c exp(2*z_i[b].z_k[c]) ) - pos_b*2 ]
// R4: persistent-A **in registers** (af[8][4], loaded once from L2-hot global),
// B streamed through a 4-deep LDS ring (stage depth 2, vmcnt(4), ONE barrier
// per K-step). 128x128 wave-tile layout unchanged; exp fused per tile;
// shuffle-reduce + atomics once per block.

constexpr int   D_DIM = 256;
constexpr float INV_T = 2.0f;   // 1/T, T=0.5

constexpr int BM = 128;
constexpr int BN = 128;
constexpr int BK = 32;
constexpr int NT = 8;           // column tiles per block (each 128 cols)

typedef __attribute__((ext_vector_type(8))) short  bf16x8;
typedef __attribute__((ext_vector_type(4))) float  f32x4;

__device__ __forceinline__ unsigned short f32_to_bf16(float f) {
    unsigned int u = __float_as_uint(f);
    u += 0x7FFFu + ((u >> 16) & 1u);          // RNE
    return (unsigned short)(u >> 16);
}

__device__ __forceinline__ void gload_lds16(const void* g, void* l) {
    auto gp = reinterpret_cast<const __attribute__((address_space(1))) unsigned int*>(
        reinterpret_cast<uintptr_t>(g));
    auto lp = reinterpret_cast<__attribute__((address_space(3))) unsigned int*>(
        reinterpret_cast<uintptr_t>(l));
    __builtin_amdgcn_global_load_lds(gp, lp, 16, 0, 0);
}

// ---------------------------------------------------------------------------
// Kernel 1: per-row norms; write normalized bf16 z_i, z_k; fp32 pos_logit.
// Also zero-initializes rowsum.
// ---------------------------------------------------------------------------
__global__ __launch_bounds__(256) void prep_kernel(
    const float* __restrict__ ei, const float* __restrict__ ej,
    const float* __restrict__ ek,
    unsigned short* __restrict__ zi, unsigned short* __restrict__ zk,
    float* __restrict__ pos_logit, float* __restrict__ rowsum, int B)
{
    const int w    = (int)((blockIdx.x * blockDim.x + threadIdx.x) >> 6);
    const int lane = (int)(threadIdx.x & 63);
    if (w >= B) return;

    const float4 vi = ((const float4*)(ei + (size_t)w * D_DIM))[lane];
    const float4 vj = ((const float4*)(ej + (size_t)w * D_DIM))[lane];
    const float4 vk = ((const float4*)(ek + (size_t)w * D_DIM))[lane];

    float ssi = vi.x*vi.x + vi.y*vi.y + vi.z*vi.z + vi.w*vi.w;
    float ssj = vj.x*vj.x + vj.y*vj.y + vj.z*vj.z + vj.w*vj.w;
    float ssk = vk.x*vk.x + vk.y*vk.y + vk.z*vk.z + vk.w*vk.w;
    float dij = vi.x*vj.x + vi.y*vj.y + vi.z*vj.z + vi.w*vj.w;

    #pragma unroll
    for (int off = 32; off; off >>= 1) {
        ssi += __shfl_xor(ssi, off);
        ssj += __shfl_xor(ssj, off);
        ssk += __shfl_xor(ssk, off);
        dij += __shfl_xor(dij, off);
    }
    const float ri = 1.0f / fmaxf(sqrtf(ssi), 1e-12f);
    const float rj = 1.0f / fmaxf(sqrtf(ssj), 1e-12f);
    const float rk = 1.0f / fmaxf(sqrtf(ssk), 1e-12f);

    ushort4 oi, ok;
    oi.x = f32_to_bf16(vi.x * ri); oi.y = f32_to_bf16(vi.y * ri);
    oi.z = f32_to_bf16(vi.z * ri); oi.w = f32_to_bf16(vi.w * ri);
    ok.x = f32_to_bf16(vk.x * rk); ok.y = f32_to_bf16(vk.y * rk);
    ok.z = f32_to_bf16(vk.z * rk); ok.w = f32_to_bf16(vk.w * rk);
    ((ushort4*)(zi + (size_t)w * D_DIM))[lane] = oi;
    ((ushort4*)(zk + (size_t)w * D_DIM))[lane] = ok;

    if (lane == 0) {
        pos_logit[w] = dij * ri * rj * INV_T;
        rowsum[w]    = 0.0f;
    }
}

// ---------------------------------------------------------------------------
// Kernel 2: rows [by*128,+128) x cols [bx*1024,+1024) of C = Z_i . Z_k^T.
// A panel in REGISTERS (af[8][4] per wave, 128 VGPR, loaded once from global);
// B streamed over 64 K-steps through a 4-deep LDS ring, stage depth 2,
// vmcnt(4), one s_barrier per step. 4 waves (2x2), wave tile 64x64 =
// 4x4 frags of 16x16x32 bf16 MFMA.
// B swizzle (verified: conflicts=0): LDS[row][c] = global[row][c ^ swz(row)]
// via pre-swizzled global source (linear LDS dest, rule 21).
// ---------------------------------------------------------------------------
__global__ __launch_bounds__(256, 2) void sim_mfma_kernel(
    const unsigned short* __restrict__ zi, const unsigned short* __restrict__ zk,
    float* __restrict__ rowsum)
{
    __shared__ unsigned short Bs[4][BN * BK];      // 4 x 8 KB ring

    const int t  = (int)threadIdx.x;
    const int w  = t >> 6;        // wave 0..3
    const int l  = t & 63;
    const int wr = w >> 1;        // wave row (0..1)
    const int wc = w & 1;         // wave col (0..1)
    const int rowBase = (int)blockIdx.y * BM;
    const int colBase = (int)blockIdx.x * (NT * BN);

    // ---- A fragments -> registers (once). Frag (kt,mi): lane l holds
    // row rowBase+wr*64+mi*16+(l&15), k elems kt*32+(l>>4)*8 .. +8.
    const int rA = l & 15;
    const int ks = (l >> 4) * 8;
    bf16x8 af[8][4];
    #pragma unroll
    for (int mi = 0; mi < 4; ++mi) {
        const unsigned short* rowp =
            zi + (size_t)(rowBase + wr * 64 + mi * 16 + rA) * D_DIM + ks;
        #pragma unroll
        for (int kt = 0; kt < 8; ++kt)
            af[kt][mi] = *(const bf16x8*)(rowp + kt * BK);
    }

    // ---- B staging addresses (per-lane constants) ----
    // wave w, instr q in {0,1}: rows [w*32+q*16,+16); lane l -> row +(l>>2),
    // 16B unit (l&3); source col pre-swizzled (elems).
    const int csrc = 8 * ((l & 3) ^ ((l >> 3) & 3));
    const unsigned short* gB0 =
        zk + (size_t)(colBase + w * 32 + (l >> 2)) * D_DIM + csrc;
    const int bQ0 = w * 1024;          // LDS element base (wave-uniform)
    const int bQ1 = bQ0 + 512;

    // stage B for global K-step s (s = tile*8 + kt) into ring slot
    #define STAGEB(slot, s) {                                                \
        const unsigned short* src = gB0                                      \
            + (size_t)((s) >> 3) * (BN * D_DIM) + (size_t)((s) & 7) * BK;    \
        gload_lds16(src,              &Bs[slot][bQ0]);                       \
        gload_lds16(src + 16 * D_DIM, &Bs[slot][bQ1]);                       \
    }

    STAGEB(0, 0);
    STAGEB(1, 1);

    // B fragment read offset (swizzled k-col, elems)
    const int ce = 8 * ((l >> 4) ^ ((rA >> 1) & 3));

    float partAcc[4][4] = {};    // per-(mi,reg) running exp-sums across tiles

    for (int nt = 0; nt < NT; ++nt) {
        f32x4 acc[4][4] = {};

        #pragma unroll
        for (int kt = 0; kt < 8; ++kt) {
            // slot arithmetic: s = nt*8+kt, nt*8 % 4 == 0 -> slots are
            // compile-time (kt&3 read, (kt+2)&3 stage).
            int s2 = nt * 8 + kt + 2;
            if (s2 > 63) s2 = 63;            // junk restage at the tail: ok
            STAGEB((kt + 2) & 3, s2);
            asm volatile("s_waitcnt vmcnt(4)" ::: "memory");  // B(s) landed
            __builtin_amdgcn_s_barrier();
            asm volatile("" ::: "memory");

            bf16x8 bfr[4];
            #pragma unroll
            for (int ni = 0; ni < 4; ++ni)
                bfr[ni] = *(const bf16x8*)
                    &Bs[kt & 3][(wc * 64 + ni * 16 + rA) * BK + ce];

            #pragma unroll
            for (int mi = 0; mi < 4; ++mi)
                #pragma unroll
                for (int ni = 0; ni < 4; ++ni)
                    acc[mi][ni] = __builtin_amdgcn_mfma_f32_16x16x32_bf16(
                        af[kt][mi], bfr[ni], acc[mi][ni], 0, 0, 0);
        }

        // per-tile epilogue: exp + in-lane partial sums (no shuffles here)
        #pragma unroll
        for (int mi = 0; mi < 4; ++mi)
            #pragma unroll
            for (int r = 0; r < 4; ++r) {
                float s = 0.f;
                #pragma unroll
                for (int ni = 0; ni < 4; ++ni)
                    s += __expf(INV_T * acc[mi][ni][r]);
                partAcc[mi][r] += s;
            }
    }
    #undef STAGEB

    // block epilogue: reduce across the 16 column-lanes, one atomic set
    #pragma unroll
    for (int off = 1; off <= 8; off <<= 1)
        #pragma unroll
        for (int mi = 0; mi < 4; ++mi)
            #pragma unroll
            for (int r = 0; r < 4; ++r)
                partAcc[mi][r] += __shfl_xor(partAcc[mi][r], off);

    if ((l & 15) == 0) {
        const int rg = (l >> 4) * 4;     // C/D layout: row = (l>>4)*4 + reg
        #pragma unroll
        for (int mi = 0; mi < 4; ++mi)
            #pragma unroll
            for (int r = 0; r < 4; ++r)
                atomicAdd(&rowsum[rowBase + wr * 64 + mi * 16 + rg + r],
                          partAcc[mi][r]);
    }
}

// ---------------------------------------------------------------------------
// Kernel 3: loss = mean_b [ log(exp(pos_b) + rowsum_b) - pos_b ]
// ---------------------------------------------------------------------------
__global__ __launch_bounds__(1024) void finalize_kernel(
    const float* __restrict__ pos_logit, const float* __restrict__ rowsum,
    float* __restrict__ out, int B)
{
    __shared__ float red[1024];
    float acc = 0.f;
    for (int b = (int)threadIdx.x; b < B; b += 1024) {
        const float pl = pos_logit[b];
        acc += logf(expf(pl) + rowsum[b]) - pl;
    }
    red[threadIdx.x] = acc;
    __syncthreads();
    #pragma unroll
    for (int s = 512; s; s >>= 1) {
        if ((int)threadIdx.x < s) red[threadIdx.x] += red[threadIdx.x + s];
        __syncthreads();
    }
    if (threadIdx.x == 0) out[0] = red[0] / (float)B;
}

// ---------------------------------------------------------------------------
extern "C" void kernel_launch(void* const* d_in, const int* in_sizes, int n_in,
                              void* d_out, int out_size, void* d_ws, size_t ws_size,
                              hipStream_t stream)
{
    const float* ei = (const float*)d_in[0];
    const float* ej = (const float*)d_in[1];
    const float* ek = (const float*)d_in[2];
    const int B = in_sizes[0] / D_DIM;   // 8192

    unsigned short* zi = (unsigned short*)d_ws;
    unsigned short* zk = zi + (size_t)B * D_DIM;
    float* rowsum      = (float*)(zk + (size_t)B * D_DIM);
    float* pos_logit   = rowsum + B;

    prep_kernel<<<dim3((B + 3) / 4), dim3(256), 0, stream>>>(
        ei, ej, ek, zi, zk, pos_logit, rowsum, B);

    dim3 grid(B / (NT * BN), B / BM);    // (8, 64) = 512 blocks = 2/CU
    sim_mfma_kernel<<<grid, dim3(256), 0, stream>>>(zi, zk, rowsum);

    finalize_kernel<<<dim3(1), dim3(1024), 0, stream>>>(
        pos_logit, rowsum, (float*)d_out, B);
}